// Round 5
// baseline (410.879 us; speedup 1.0000x reference)
//
#include <hip/hip_runtime.h>

#define N_INNER 2000
#define N_LEAF  10000
#define N_DOC   128

#define NBLK  376
#define AMAXB 250            // blocks 0..249 argmax, 250..375 mass dist tiles
#define MCH   156            // mass-only 64-col chunks, feat cols [2016,12000)
#define PCH   63             // proj-region 32-col chunks, feat cols [0,2016)

// ws byte offsets (barrier+packed zeroed by one small memset each launch)
#define WS_BAR     0
#define WS_PACKED  128
#define WS_PROJ    81920
#define WS_S       1105920
#define WS_PART    1106432   // 126 rows * 16384 * 4 = 8,257,536
#define WS_MRED    9363968   // 16384 * 4

__device__ __forceinline__ unsigned enc_f32(float f) {
    unsigned u = __float_as_uint(f);
    return (u & 0x80000000u) ? ~u : (u | 0x80000000u);   // monotone float->uint
}

// ---- manual grid barrier: monotonic counter, device-scope, co-resident grid ----
__device__ __forceinline__ void grid_bar(unsigned* cnt, unsigned target) {
    __syncthreads();
    if (threadIdx.x == 0) {
        __threadfence();                                   // release (L2 wb)
        __hip_atomic_fetch_add(cnt, 1u, __ATOMIC_ACQ_REL, __HIP_MEMORY_SCOPE_AGENT);
        while (__hip_atomic_load(cnt, __ATOMIC_ACQUIRE, __HIP_MEMORY_SCOPE_AGENT) < target)
            __builtin_amdgcn_s_sleep(2);
        __threadfence();                                   // acquire (inv stale)
    }
    __syncthreads();
}

// ---- argmax work unit: 1024-col stripe x 40-row chunk, packed u64 atomicMax ----
__device__ __forceinline__ void amax_unit(const float* __restrict__ param,
                                          unsigned long long* __restrict__ packed,
                                          int u, int t) {
    int stripe = u / 50, rc = u % 50;
    int j0 = (stripe * 256 + t) * 4;
    if (j0 >= N_LEAF) return;            // no syncthreads inside this fn
    int r0 = rc * 40;
    float b0 = -1e30f, b1 = -1e30f, b2 = -1e30f, b3 = -1e30f;
    unsigned i0 = 0, i1 = 0, i2 = 0, i3 = 0;
    const float* p = param + (size_t)r0 * N_LEAF + j0;
    #pragma unroll 8
    for (int r = 0; r < 40; ++r) {
        float4 v = *(const float4*)p;
        p += N_LEAF;
        unsigned row = (unsigned)(r0 + r);
        if (v.x > b0) { b0 = v.x; i0 = row; }
        if (v.y > b1) { b1 = v.y; i1 = row; }
        if (v.z > b2) { b2 = v.z; i2 = row; }
        if (v.w > b3) { b3 = v.w; i3 = row; }
    }
    atomicMax(&packed[j0 + 0], ((unsigned long long)enc_f32(b0) << 32) | i0);
    atomicMax(&packed[j0 + 1], ((unsigned long long)enc_f32(b1) << 32) | i1);
    atomicMax(&packed[j0 + 2], ((unsigned long long)enc_f32(b2) << 32) | i2);
    atomicMax(&packed[j0 + 3], ((unsigned long long)enc_f32(b3) << 32) | i3);
}

// ---- stage+accumulate one mass 64-col chunk into acc (tile 128i x 64j) ----
__device__ __forceinline__ void mass_tile_acc(const float* __restrict__ mass,
                                              float* lds, int c, int jbase, int t,
                                              float acc[8][4]) {
    int mc0 = 16 + c * 64;               // mass col base (feat col 2016 + c*64)
    __syncthreads();                     // protect LDS from previous readers
    #pragma unroll
    for (int k = 0; k < 12; ++k) {
        int f = t + k * 256;             // 3072 float4 slots = 192 rows x 16 groups
        int row = f >> 4, g = f & 15;
        int doc = (row < 128) ? row : (jbase + (row - 128));
        float4 v = *(const float4*)(mass + (size_t)doc * N_LEAF + mc0 + g * 4);
        int gg = g ^ ((row >> 3) & 7);
        *(float4*)(&lds[row * 64 + gg * 4]) = v;
    }
    __syncthreads();
    int tx = t & 15, ty = t >> 4;
    int ib = ty * 8;
    int jb = 128 + tx * 4;
    int swi = ty & 7;                    // ((ty*8+r)>>3)&7 == ty&7
    int swj = (tx >> 1) & 7;             // ((128+tx*4+jr)>>3)&7
    #pragma unroll 4
    for (int cgi = 0; cgi < 16; ++cgi) {
        float4 bv[4];
        #pragma unroll
        for (int jr = 0; jr < 4; ++jr)
            bv[jr] = *(const float4*)(&lds[(jb + jr) * 64 + ((cgi ^ swj) << 2)]);
        #pragma unroll
        for (int r = 0; r < 8; ++r) {
            float4 av = *(const float4*)(&lds[(ib + r) * 64 + ((cgi ^ swi) << 2)]);
            #pragma unroll
            for (int q = 0; q < 4; ++q) {
                acc[r][q] += (fminf(av.x, bv[q].x) + fminf(av.y, bv[q].y))
                           + (fminf(av.z, bv[q].z) + fminf(av.w, bv[q].w));
            }
        }
    }
}

// ---- proj-region tile: 128i x 64j x 32 cols from feat[c*32..), writes row 63+c ----
__device__ __forceinline__ void proj_tile(const float* __restrict__ proj,
                                          const float* __restrict__ mass,
                                          float* __restrict__ partial,
                                          float* lds, int c, int jbase, int t) {
    int f0 = c * 32;
    __syncthreads();
    #pragma unroll
    for (int k = 0; k < 6; ++k) {
        int f = t + k * 256;             // 1536 float4 slots = 192 rows x 8 groups
        int row = f >> 3, g = f & 7;
        int doc = (row < 128) ? row : (jbase + (row - 128));
        int col = f0 + g * 4;
        float4 v;
        if (col < N_INNER) v = *(const float4*)(proj + (size_t)doc * N_INNER + col);
        else               v = *(const float4*)(mass + (size_t)doc * N_LEAF + (col - N_INNER));
        int gg = g ^ ((row >> 2) & 7);
        *(float4*)(&lds[row * 32 + gg * 4]) = v;
    }
    __syncthreads();
    int tx = t & 15, ty = t >> 4;
    int ib = ty * 8;
    int jb = 128 + tx * 4;
    int swj = tx & 7;                    // ((128+tx*4+jr)>>2)&7 == tx&7
    float acc[8][4] = {};
    #pragma unroll
    for (int cgi = 0; cgi < 8; ++cgi) {
        float4 bv[4];
        #pragma unroll
        for (int jr = 0; jr < 4; ++jr)
            bv[jr] = *(const float4*)(&lds[(jb + jr) * 32 + ((cgi ^ swj) << 2)]);
        #pragma unroll
        for (int r = 0; r < 8; ++r) {
            int swi = ((ib + r) >> 2) & 7;
            float4 av = *(const float4*)(&lds[(ib + r) * 32 + ((cgi ^ swi) << 2)]);
            #pragma unroll
            for (int q = 0; q < 4; ++q) {
                acc[r][q] += (fminf(av.x, bv[q].x) + fminf(av.y, bv[q].y))
                           + (fminf(av.z, bv[q].z) + fminf(av.w, bv[q].w));
            }
        }
    }
    float* pp = partial + (size_t)(PCH + c) * 16384 + jbase;
    #pragma unroll
    for (int r = 0; r < 8; ++r)
        *(float4*)(pp + (size_t)(ib + r) * 128 + tx * 4) =
            make_float4(acc[r][0], acc[r][1], acc[r][2], acc[r][3]);
}

// ---- per-doc bucket accumulation + wave scan + S + proj (LDS-resident prefix) ----
__device__ __forceinline__ void wscan_body(const unsigned long long* __restrict__ packed,
                                           const float* __restrict__ mass,
                                           float* __restrict__ proj,
                                           float* __restrict__ S,
                                           char* smem, int d, int t) {
    float* wl = (float*)smem;            // 2000
    float* Px = wl + N_INNER;            // 2001
    float* wsum  = Px + N_INNER + 1;     // 4
    float* wsum2 = wsum + 4;             // 4
    for (int k = t; k < N_INNER; k += 256) wl[k] = 0.f;
    __syncthreads();
    const float* md = mass + (size_t)d * N_LEAF;
    const unsigned* pw = (const unsigned*)packed;   // low word = argmax row (LE)
    #pragma unroll
    for (int it = 0; it < 10; ++it) {
        int j0 = (t + it * 256) * 4;
        if (j0 < N_LEAF) {
            float4 v = *(const float4*)(md + j0);
            atomicAdd(&wl[pw[2 * (j0 + 0)]], v.x);
            atomicAdd(&wl[pw[2 * (j0 + 1)]], v.y);
            atomicAdd(&wl[pw[2 * (j0 + 2)]], v.z);
            atomicAdd(&wl[pw[2 * (j0 + 3)]], v.w);
        }
    }
    __syncthreads();
    float loc[8];
    float s = 0.f, s2 = 0.f;
    #pragma unroll
    for (int k = 0; k < 8; ++k) {
        int idx = t * 8 + k;
        float v = (idx < N_INNER) ? wl[idx] : 0.f;
        loc[k] = s;
        s += v;
        float dep = (float)((idx >= 1) + (idx >= 6) + (idx >= 31) + (idx >= 156) + (idx >= 781) + 2);
        s2 += dep * v;
    }
    int lane = t & 63, w = t >> 6;
    float ws = s;
    #pragma unroll
    for (int off = 1; off < 64; off <<= 1) {
        float o = __shfl_up(ws, off, 64);
        if (lane >= off) ws += o;
    }
    float r2 = s2;
    #pragma unroll
    for (int off = 32; off > 0; off >>= 1) r2 += __shfl_down(r2, off, 64);
    if (lane == 63) wsum[w] = ws;
    if (lane == 0)  wsum2[w] = r2;
    __syncthreads();
    float base = ws - s;
    for (int q = 0; q < w; ++q) base += wsum[q];
    #pragma unroll
    for (int k = 0; k < 8; ++k) {
        int idx = t * 8 + k;
        if (idx <= N_INNER) Px[idx] = base + loc[k];
    }
    if (t == 0) S[d] = (wsum2[0] + wsum2[1]) + (wsum2[2] + wsum2[3]);
    __syncthreads();
    float* pd = proj + (size_t)d * N_INNER;
    #pragma unroll
    for (int k = 0; k < 8; ++k) {
        int i = t + k * 256;
        if (i < N_INNER) {
            float sum = 0.f;
            int s0 = i, e0 = i;
            while (s0 < N_INNER) {
                int ee = (e0 < N_INNER - 1) ? e0 : (N_INNER - 1);
                sum += Px[ee + 1] - Px[s0];
                s0 = 5 * s0 + 1;
                e0 = 5 * e0 + 5;
            }
            pd[i] = sum;
        }
    }
}

// ================================ mega kernel ================================
// Plain launch + manual barrier. Co-residency: 48KB LDS -> 3 blk/CU (LDS),
// __launch_bounds__(256,2) -> VGPR<=256 -> >=2 blk/CU -> capacity 512 >= 376.
__global__ __launch_bounds__(256, 2) void mega(const float* __restrict__ mass,
                                               const float* __restrict__ param,
                                               float* __restrict__ out,
                                               unsigned* __restrict__ bar,
                                               unsigned long long* __restrict__ packed,
                                               float* __restrict__ proj,
                                               float* __restrict__ S,
                                               float* __restrict__ partial,
                                               float* __restrict__ mred) {
    __shared__ __align__(16) char smem[49152];
    float* lds = (float*)smem;
    int bid = blockIdx.x, t = threadIdx.x;

    // ---- P1: argmax over param (blocks 0..249, HBM-bound)
    //          || 156x2 mass dist tiles, 3 col-chunks accumulated per block ----
    if (bid < AMAXB) {
        for (int u = bid; u < 500; u += AMAXB)    // exactly 2 units each
            amax_unit(param, packed, u, t);
    } else {
        int b = bid - AMAXB;                      // 0..125
        int jbase = (b & 1) * 64;
        int q = b >> 1;                           // 0..62  -> partial row q
        float acc[8][4] = {};
        #pragma unroll 1
        for (int k = 0; k < 3; ++k) {
            int c = q + 63 * k;                   // block-uniform
            if (c >= MCH) break;
            mass_tile_acc(mass, lds, c, jbase, t, acc);
        }
        int tx = t & 15, ty = t >> 4;
        float* pp = partial + (size_t)q * 16384 + jbase;
        #pragma unroll
        for (int r = 0; r < 8; ++r)
            *(float4*)(pp + (size_t)(ty * 8 + r) * 128 + tx * 4) =
                make_float4(acc[r][0], acc[r][1], acc[r][2], acc[r][3]);
    }
    grid_bar(bar, NBLK);

    // ---- P2: wscan+proj (blocks 0..127) || mass-row pre-reduce (blocks 128..191) ----
    if (bid < N_DOC) {
        wscan_body(packed, mass, proj, S, smem, bid, t);
    } else if (bid < N_DOC + 64) {
        int p = (bid - N_DOC) * 256 + t;          // 0..16383
        float s0 = 0.f, s1 = 0.f, s2 = 0.f, s3 = 0.f;
        int c = 0;
        for (; c + 4 <= 63; c += 4) {
            s0 += partial[(size_t)(c + 0) * 16384 + p];
            s1 += partial[(size_t)(c + 1) * 16384 + p];
            s2 += partial[(size_t)(c + 2) * 16384 + p];
            s3 += partial[(size_t)(c + 3) * 16384 + p];
        }
        for (; c < 63; ++c) s0 += partial[(size_t)c * 16384 + p];
        mred[p] = (s0 + s1) + (s2 + s3);
    }
    grid_bar(bar, 2 * NBLK);

    // ---- P3: proj-region dist tiles (126 blocks, 1 tile each) ----
    if (bid < 2 * PCH) {
        proj_tile(proj, mass, partial, lds, bid >> 1, (bid & 1) * 64, t);
    }
    grid_bar(bar, 3 * NBLK);

    // ---- P4: out = S_i + S_j - 2*(mred + sum of proj rows) ----
    if (bid < 64) {
        int p = bid * 256 + t;
        float s0 = mred[p], s1 = 0.f, s2 = 0.f, s3 = 0.f;
        int c = 0;
        for (; c + 4 <= PCH; c += 4) {
            s0 += partial[(size_t)(PCH + c + 0) * 16384 + p];
            s1 += partial[(size_t)(PCH + c + 1) * 16384 + p];
            s2 += partial[(size_t)(PCH + c + 2) * 16384 + p];
            s3 += partial[(size_t)(PCH + c + 3) * 16384 + p];
        }
        for (; c < PCH; ++c) s0 += partial[(size_t)(PCH + c) * 16384 + p];
        int i = p >> 7, j = p & 127;
        out[p] = S[i] + S[j] - 2.f * ((s0 + s1) + (s2 + s3));
    }
}

extern "C" void kernel_launch(void* const* d_in, const int* in_sizes, int n_in,
                              void* d_out, int out_size, void* d_ws, size_t ws_size,
                              hipStream_t stream) {
    const float* mass  = (const float*)d_in[0];   // 128 x 10000
    const float* param = (const float*)d_in[1];   // 2000 x 10000
    float* out = (float*)d_out;                   // 128 x 128
    char* ws = (char*)d_ws;

    unsigned*           bar     = (unsigned*)(ws + WS_BAR);
    unsigned long long* packed  = (unsigned long long*)(ws + WS_PACKED);
    float*              proj    = (float*)(ws + WS_PROJ);
    float*              S       = (float*)(ws + WS_S);
    float*              partial = (float*)(ws + WS_PART);
    float*              mred    = (float*)(ws + WS_MRED);

    // zero barrier counter + packed argmax keys (ws is poisoned 0xAA each run)
    hipMemsetAsync(ws, 0, WS_PACKED + N_LEAF * sizeof(unsigned long long), stream);
    mega<<<dim3(NBLK), dim3(256), 0, stream>>>(mass, param, out, bar, packed,
                                               proj, S, partial, mred);
}

// Round 6
// 260.838 us; speedup vs baseline: 1.5752x; 1.5752x over previous
//
#include <hip/hip_runtime.h>

#define N_INNER 2000
#define N_LEAF  10000
#define N_DOC   128

#define NBLK  376
#define AMAXB 250            // blocks 0..249 argmax, 250..375 mass dist tiles
#define MCH   156            // mass-only 64-col chunks, feat cols [2016,12000)
#define PCH   63             // proj-region 32-col chunks, feat cols [0,2016)

// ws byte offsets (barrier+packed zeroed by one small memset each launch)
#define WS_BAR     0
#define WS_PACKED  128
#define WS_PROJ    81920
#define WS_S       1105920
#define WS_PART    1106432   // 126 rows * 16384 * 4 = 8,257,536
#define WS_MRED    9363968   // 16384 * 4

__device__ __forceinline__ unsigned enc_f32(float f) {
    unsigned u = __float_as_uint(f);
    return (u & 0x80000000u) ? ~u : (u | 0x80000000u);   // monotone float->uint
}

// ---- manual grid barrier, cg-style: RELAXED polls (no per-poll cache-inv),
//      one release fence before arrive, one acquire fence after exit.
//      R5 post-mortem: ACQUIRE polls emit buffer_inv each poll -> 130us/barrier.
__device__ __forceinline__ void grid_bar(unsigned* cnt, unsigned target) {
    __syncthreads();
    if (threadIdx.x == 0) {
        __threadfence();                                   // release: wb L2 to coherent point
        __hip_atomic_fetch_add(cnt, 1u, __ATOMIC_RELAXED, __HIP_MEMORY_SCOPE_AGENT);
        for (;;) {
            bool done = false;
            #pragma unroll 1
            for (int k = 0; k < 64; ++k) {                 // cheap relaxed polls
                if (__hip_atomic_load(cnt, __ATOMIC_RELAXED, __HIP_MEMORY_SCOPE_AGENT) >= target) {
                    done = true; break;
                }
                __builtin_amdgcn_s_sleep(16);
            }
            if (done) break;
            // liveness fallback: one acquire poll per 64 relaxed ones
            if (__hip_atomic_load(cnt, __ATOMIC_ACQUIRE, __HIP_MEMORY_SCOPE_AGENT) >= target)
                break;
        }
        __threadfence();                                   // acquire: inv stale L1/L2
    }
    __syncthreads();
}

// ---- argmax work unit: 1024-col stripe x 40-row chunk, packed u64 atomicMax ----
__device__ __forceinline__ void amax_unit(const float* __restrict__ param,
                                          unsigned long long* __restrict__ packed,
                                          int u, int t) {
    int stripe = u / 50, rc = u % 50;
    int j0 = (stripe * 256 + t) * 4;
    if (j0 >= N_LEAF) return;            // no syncthreads inside this fn
    int r0 = rc * 40;
    float b0 = -1e30f, b1 = -1e30f, b2 = -1e30f, b3 = -1e30f;
    unsigned i0 = 0, i1 = 0, i2 = 0, i3 = 0;
    const float* p = param + (size_t)r0 * N_LEAF + j0;
    #pragma unroll 8
    for (int r = 0; r < 40; ++r) {
        float4 v = *(const float4*)p;
        p += N_LEAF;
        unsigned row = (unsigned)(r0 + r);
        if (v.x > b0) { b0 = v.x; i0 = row; }
        if (v.y > b1) { b1 = v.y; i1 = row; }
        if (v.z > b2) { b2 = v.z; i2 = row; }
        if (v.w > b3) { b3 = v.w; i3 = row; }
    }
    atomicMax(&packed[j0 + 0], ((unsigned long long)enc_f32(b0) << 32) | i0);
    atomicMax(&packed[j0 + 1], ((unsigned long long)enc_f32(b1) << 32) | i1);
    atomicMax(&packed[j0 + 2], ((unsigned long long)enc_f32(b2) << 32) | i2);
    atomicMax(&packed[j0 + 3], ((unsigned long long)enc_f32(b3) << 32) | i3);
}

// ---- stage+accumulate one mass 64-col chunk into acc (tile 128i x 64j) ----
__device__ __forceinline__ void mass_tile_acc(const float* __restrict__ mass,
                                              float* lds, int c, int jbase, int t,
                                              float acc[8][4]) {
    int mc0 = 16 + c * 64;               // mass col base (feat col 2016 + c*64)
    __syncthreads();                     // protect LDS from previous readers
    #pragma unroll
    for (int k = 0; k < 12; ++k) {
        int f = t + k * 256;             // 3072 float4 slots = 192 rows x 16 groups
        int row = f >> 4, g = f & 15;
        int doc = (row < 128) ? row : (jbase + (row - 128));
        float4 v = *(const float4*)(mass + (size_t)doc * N_LEAF + mc0 + g * 4);
        int gg = g ^ ((row >> 3) & 7);
        *(float4*)(&lds[row * 64 + gg * 4]) = v;
    }
    __syncthreads();
    int tx = t & 15, ty = t >> 4;
    int ib = ty * 8;
    int jb = 128 + tx * 4;
    int swi = ty & 7;                    // ((ty*8+r)>>3)&7 == ty&7
    int swj = (tx >> 1) & 7;             // ((128+tx*4+jr)>>3)&7
    #pragma unroll 4
    for (int cgi = 0; cgi < 16; ++cgi) {
        float4 bv[4];
        #pragma unroll
        for (int jr = 0; jr < 4; ++jr)
            bv[jr] = *(const float4*)(&lds[(jb + jr) * 64 + ((cgi ^ swj) << 2)]);
        #pragma unroll
        for (int r = 0; r < 8; ++r) {
            float4 av = *(const float4*)(&lds[(ib + r) * 64 + ((cgi ^ swi) << 2)]);
            #pragma unroll
            for (int q = 0; q < 4; ++q) {
                acc[r][q] += (fminf(av.x, bv[q].x) + fminf(av.y, bv[q].y))
                           + (fminf(av.z, bv[q].z) + fminf(av.w, bv[q].w));
            }
        }
    }
}

// ---- proj-region tile: 128i x 64j x 32 cols from feat[c*32..), writes row 63+c ----
__device__ __forceinline__ void proj_tile(const float* __restrict__ proj,
                                          const float* __restrict__ mass,
                                          float* __restrict__ partial,
                                          float* lds, int c, int jbase, int t) {
    int f0 = c * 32;
    __syncthreads();
    #pragma unroll
    for (int k = 0; k < 6; ++k) {
        int f = t + k * 256;             // 1536 float4 slots = 192 rows x 8 groups
        int row = f >> 3, g = f & 7;
        int doc = (row < 128) ? row : (jbase + (row - 128));
        int col = f0 + g * 4;
        float4 v;
        if (col < N_INNER) v = *(const float4*)(proj + (size_t)doc * N_INNER + col);
        else               v = *(const float4*)(mass + (size_t)doc * N_LEAF + (col - N_INNER));
        int gg = g ^ ((row >> 2) & 7);
        *(float4*)(&lds[row * 32 + gg * 4]) = v;
    }
    __syncthreads();
    int tx = t & 15, ty = t >> 4;
    int ib = ty * 8;
    int jb = 128 + tx * 4;
    int swj = tx & 7;                    // ((128+tx*4+jr)>>2)&7 == tx&7
    float acc[8][4] = {};
    #pragma unroll
    for (int cgi = 0; cgi < 8; ++cgi) {
        float4 bv[4];
        #pragma unroll
        for (int jr = 0; jr < 4; ++jr)
            bv[jr] = *(const float4*)(&lds[(jb + jr) * 32 + ((cgi ^ swj) << 2)]);
        #pragma unroll
        for (int r = 0; r < 8; ++r) {
            int swi = ((ib + r) >> 2) & 7;
            float4 av = *(const float4*)(&lds[(ib + r) * 32 + ((cgi ^ swi) << 2)]);
            #pragma unroll
            for (int q = 0; q < 4; ++q) {
                acc[r][q] += (fminf(av.x, bv[q].x) + fminf(av.y, bv[q].y))
                           + (fminf(av.z, bv[q].z) + fminf(av.w, bv[q].w));
            }
        }
    }
    float* pp = partial + (size_t)(PCH + c) * 16384 + jbase;
    #pragma unroll
    for (int r = 0; r < 8; ++r)
        *(float4*)(pp + (size_t)(ib + r) * 128 + tx * 4) =
            make_float4(acc[r][0], acc[r][1], acc[r][2], acc[r][3]);
}

// ---- per-doc bucket accumulation + wave scan + S + proj (LDS-resident prefix) ----
__device__ __forceinline__ void wscan_body(const unsigned long long* __restrict__ packed,
                                           const float* __restrict__ mass,
                                           float* __restrict__ proj,
                                           float* __restrict__ S,
                                           char* smem, int d, int t) {
    float* wl = (float*)smem;            // 2000
    float* Px = wl + N_INNER;            // 2001
    float* wsum  = Px + N_INNER + 1;     // 4
    float* wsum2 = wsum + 4;             // 4
    for (int k = t; k < N_INNER; k += 256) wl[k] = 0.f;
    __syncthreads();
    const float* md = mass + (size_t)d * N_LEAF;
    const unsigned* pw = (const unsigned*)packed;   // low word = argmax row (LE)
    #pragma unroll
    for (int it = 0; it < 10; ++it) {
        int j0 = (t + it * 256) * 4;
        if (j0 < N_LEAF) {
            float4 v = *(const float4*)(md + j0);
            atomicAdd(&wl[pw[2 * (j0 + 0)]], v.x);
            atomicAdd(&wl[pw[2 * (j0 + 1)]], v.y);
            atomicAdd(&wl[pw[2 * (j0 + 2)]], v.z);
            atomicAdd(&wl[pw[2 * (j0 + 3)]], v.w);
        }
    }
    __syncthreads();
    float loc[8];
    float s = 0.f, s2 = 0.f;
    #pragma unroll
    for (int k = 0; k < 8; ++k) {
        int idx = t * 8 + k;
        float v = (idx < N_INNER) ? wl[idx] : 0.f;
        loc[k] = s;
        s += v;
        float dep = (float)((idx >= 1) + (idx >= 6) + (idx >= 31) + (idx >= 156) + (idx >= 781) + 2);
        s2 += dep * v;
    }
    int lane = t & 63, w = t >> 6;
    float ws = s;
    #pragma unroll
    for (int off = 1; off < 64; off <<= 1) {
        float o = __shfl_up(ws, off, 64);
        if (lane >= off) ws += o;
    }
    float r2 = s2;
    #pragma unroll
    for (int off = 32; off > 0; off >>= 1) r2 += __shfl_down(r2, off, 64);
    if (lane == 63) wsum[w] = ws;
    if (lane == 0)  wsum2[w] = r2;
    __syncthreads();
    float base = ws - s;
    for (int q = 0; q < w; ++q) base += wsum[q];
    #pragma unroll
    for (int k = 0; k < 8; ++k) {
        int idx = t * 8 + k;
        if (idx <= N_INNER) Px[idx] = base + loc[k];
    }
    if (t == 0) S[d] = (wsum2[0] + wsum2[1]) + (wsum2[2] + wsum2[3]);
    __syncthreads();
    float* pd = proj + (size_t)d * N_INNER;
    #pragma unroll
    for (int k = 0; k < 8; ++k) {
        int i = t + k * 256;
        if (i < N_INNER) {
            float sum = 0.f;
            int s0 = i, e0 = i;
            while (s0 < N_INNER) {
                int ee = (e0 < N_INNER - 1) ? e0 : (N_INNER - 1);
                sum += Px[ee + 1] - Px[s0];
                s0 = 5 * s0 + 1;
                e0 = 5 * e0 + 5;
            }
            pd[i] = sum;
        }
    }
}

// ================================ mega kernel ================================
// Plain launch + manual barrier. Co-residency: 48KB LDS -> 3 blk/CU (LDS),
// __launch_bounds__(256,2) -> >=2 blk/CU by VGPR -> capacity >= 512 >= 376.
__global__ __launch_bounds__(256, 2) void mega(const float* __restrict__ mass,
                                               const float* __restrict__ param,
                                               float* __restrict__ out,
                                               unsigned* __restrict__ bar,
                                               unsigned long long* __restrict__ packed,
                                               float* __restrict__ proj,
                                               float* __restrict__ S,
                                               float* __restrict__ partial,
                                               float* __restrict__ mred) {
    __shared__ __align__(16) char smem[49152];
    float* lds = (float*)smem;
    int bid = blockIdx.x, t = threadIdx.x;

    // ---- P1: argmax over param (blocks 0..249, HBM-bound)
    //          || 156x2 mass dist tiles, 3 col-chunks accumulated per block ----
    if (bid < AMAXB) {
        for (int u = bid; u < 500; u += AMAXB)    // exactly 2 units each
            amax_unit(param, packed, u, t);
    } else {
        int b = bid - AMAXB;                      // 0..125
        int jbase = (b & 1) * 64;
        int q = b >> 1;                           // 0..62  -> partial row q
        float acc[8][4] = {};
        #pragma unroll 1
        for (int k = 0; k < 3; ++k) {
            int c = q + 63 * k;                   // block-uniform
            if (c >= MCH) break;
            mass_tile_acc(mass, lds, c, jbase, t, acc);
        }
        int tx = t & 15, ty = t >> 4;
        float* pp = partial + (size_t)q * 16384 + jbase;
        #pragma unroll
        for (int r = 0; r < 8; ++r)
            *(float4*)(pp + (size_t)(ty * 8 + r) * 128 + tx * 4) =
                make_float4(acc[r][0], acc[r][1], acc[r][2], acc[r][3]);
    }
    grid_bar(bar, NBLK);

    // ---- P2: wscan+proj (blocks 0..127) || mass-row pre-reduce (blocks 128..191) ----
    if (bid < N_DOC) {
        wscan_body(packed, mass, proj, S, smem, bid, t);
    } else if (bid < N_DOC + 64) {
        int p = (bid - N_DOC) * 256 + t;          // 0..16383
        float s0 = 0.f, s1 = 0.f, s2 = 0.f, s3 = 0.f;
        int c = 0;
        for (; c + 4 <= 63; c += 4) {
            s0 += partial[(size_t)(c + 0) * 16384 + p];
            s1 += partial[(size_t)(c + 1) * 16384 + p];
            s2 += partial[(size_t)(c + 2) * 16384 + p];
            s3 += partial[(size_t)(c + 3) * 16384 + p];
        }
        for (; c < 63; ++c) s0 += partial[(size_t)c * 16384 + p];
        mred[p] = (s0 + s1) + (s2 + s3);
    }
    grid_bar(bar, 2 * NBLK);

    // ---- P3: proj-region dist tiles (126 blocks, 1 tile each) ----
    if (bid < 2 * PCH) {
        proj_tile(proj, mass, partial, lds, bid >> 1, (bid & 1) * 64, t);
    }
    grid_bar(bar, 3 * NBLK);

    // ---- P4: out = S_i + S_j - 2*(mred + sum of proj rows) ----
    if (bid < 64) {
        int p = bid * 256 + t;
        float s0 = mred[p], s1 = 0.f, s2 = 0.f, s3 = 0.f;
        int c = 0;
        for (; c + 4 <= PCH; c += 4) {
            s0 += partial[(size_t)(PCH + c + 0) * 16384 + p];
            s1 += partial[(size_t)(PCH + c + 1) * 16384 + p];
            s2 += partial[(size_t)(PCH + c + 2) * 16384 + p];
            s3 += partial[(size_t)(PCH + c + 3) * 16384 + p];
        }
        for (; c < PCH; ++c) s0 += partial[(size_t)(PCH + c) * 16384 + p];
        int i = p >> 7, j = p & 127;
        out[p] = S[i] + S[j] - 2.f * ((s0 + s1) + (s2 + s3));
    }
}

extern "C" void kernel_launch(void* const* d_in, const int* in_sizes, int n_in,
                              void* d_out, int out_size, void* d_ws, size_t ws_size,
                              hipStream_t stream) {
    const float* mass  = (const float*)d_in[0];   // 128 x 10000
    const float* param = (const float*)d_in[1];   // 2000 x 10000
    float* out = (float*)d_out;                   // 128 x 128
    char* ws = (char*)d_ws;

    unsigned*           bar     = (unsigned*)(ws + WS_BAR);
    unsigned long long* packed  = (unsigned long long*)(ws + WS_PACKED);
    float*              proj    = (float*)(ws + WS_PROJ);
    float*              S       = (float*)(ws + WS_S);
    float*              partial = (float*)(ws + WS_PART);
    float*              mred    = (float*)(ws + WS_MRED);

    // zero barrier counter + packed argmax keys (ws is poisoned 0xAA each run)
    hipMemsetAsync(ws, 0, WS_PACKED + N_LEAF * sizeof(unsigned long long), stream);
    mega<<<dim3(NBLK), dim3(256), 0, stream>>>(mass, param, out, bar, packed,
                                               proj, S, partial, mred);
}